// Round 9
// baseline (204.566 us; speedup 1.0000x reference)
//
#include <hip/hip_runtime.h>
#include <cstddef>

// BoardModel: B=16384. out = [xf(32), a_mean(32), b2(32)] per sample, then board (3,22,12).
// MHA is degenerate (kv len 1 -> softmax==1): a_mean = out_proj(in_proj[64:96] @ b2 + b).
//
// R9 = R8 + v_pk_fma_f32 (packed fp32) restructuring:
//   - float2 (ext_vector) accumulators in conv1/conv2/tail GEMVs -> LLVM selects
//     v_pk_fma_f32 (2 FMA/inst, full-rate on CDNA).
//   - weights repacked TAP-MAJOR (o fastest) into d_ws by the precompute kernel so
//     every weight pair is a contiguous 8B-aligned 64-bit scalar operand.
//   - everything else identical to R8 (dead P1 row removed, wave=sample phase B,
//     SGPR dense weights, LDS ~20KB, NO min-waves bound).

typedef float f32x2 __attribute__((ext_vector_type(2)));

#define BATCH 16384
#define SPB   4
#define NBLK  (BATCH / SPB)
#define RS    18
#define P1OFF  432          // P1: [o*61 + p], p<60
#define PCSOFF 800          // 16 ints
#define SS2    816          // floats per sample
// d_ws layout (floats): cb 1584 @0, w1p 150 @1584, w2p 2400 @1734
#define WS_W1P 1584
#define WS_W2P 1734

// ---- precompute: C_border + tap-major weight repacks ----
__global__ __launch_bounds__(256)
void precomp_kernel(const float* __restrict__ w1, const float* __restrict__ w2,
                    float* __restrict__ ws)
{
  int i = blockIdx.x * 256 + threadIdx.x;
  if (i < 1584) {
    int p = i / 6, o = i - p * 6;
    int y0 = p / 12, x0 = p - y0 * 12;
    float acc = 0.f;
#pragma unroll
    for (int dy = 0; dy < 5; ++dy)
#pragma unroll
      for (int dx = 0; dx < 5; ++dx) {
        int pr = y0 + dy - 2, pc = x0 + dx - 2;
        if (pr >= 0 && pr < 22 && pc >= 0 && pc < 12 &&
            (pr == 21 || pc == 0 || pc == 11)) {
          int k = dy * 5 + dx;
          acc += w1[(o * 3 + 0) * 25 + k] + w1[(o * 3 + 1) * 25 + k]
               + w1[(o * 3 + 2) * 25 + k];
        }
      }
    ws[i] = acc;
  } else if (i < 1734) {
    int j = i - 1584;                 // w1p[tap*6+o] = w1 ch0
    int tap = j / 6, o = j - tap * 6;
    ws[i] = w1[o * 75 + tap];
  } else if (i < 4134) {
    int j = i - 1734;                 // w2p[tap*16+oc] = w2[oc*150+tap]
    int tap = j >> 4, oc = j & 15;
    ws[i] = w2[oc * 150 + tap];
  }
}

__global__ __launch_bounds__(256)
void board_model_kernel(const int* __restrict__ t,           // (B,232)
                        const int* __restrict__ piece_table, // (8,4,4,4)
                        const float* __restrict__ w1, const float* __restrict__ b1,
                        const float* __restrict__ b2w,
                        const float* __restrict__ w3, const float* __restrict__ b3,
                        const float* __restrict__ wf1, const float* __restrict__ bf1,
                        const float* __restrict__ fcw, const float* __restrict__ fcb,
                        const float* __restrict__ ipw, const float* __restrict__ ipb,
                        const float* __restrict__ opw, const float* __restrict__ opb,
                        const float* __restrict__ ws,         // cb | w1p | w2p
                        float* __restrict__ out,              // (B,96)
                        float* __restrict__ out_board)        // (B,3,22,12)
{
  __shared__ __align__(16) float scr[SPB * SS2];
  __shared__ float w1L[300];     // ch1/ch2 taps: [(o*2+(ch-1))*25 + k]
  __shared__ float cbL[1440];    // conv cells rows 0..19

  const int tid  = threadIdx.x;
  const int lane = tid & 63;
  const int wv   = tid >> 6;          // wave id == sample slot
  const int bb   = blockIdx.x * SPB;

  const f32x2* w1p2 = (const f32x2*)(ws + WS_W1P);   // [tap*3 + o2]
  const f32x2* w2p2 = (const f32x2*)(ws + WS_W2P);   // [tap*8 + oc2]

  for (int i = tid; i < 300; i += 256)
    w1L[i] = w1[(i / 50) * 75 + 25 + (i % 50)];
  for (int i = tid; i < 1440; i += 256) cbL[i] = ws[i];

  // ---------------- Phase A: per-wave board build + board output ----------------
  {
    float* W = &scr[wv * SS2];
    int*   pcs = (int*)&scr[wv * SS2 + PCSOFF];
    const int* tr = t + (size_t)(bb + wv) * 232;

    float4* W4 = (float4*)W;
    for (int i = lane; i < 108; i += 64) W4[i] = float4{0.f, 0.f, 0.f, 0.f};

    for (int i = lane; i < 210; i += 64) {
      int r = i / 10, b = i - r * 10;
      W[(r + 2) * RS + b + 5] = (float)tr[22 + i];
    }

    if (lane < 4) {
      const int* pt = piece_table + (tr[8] * 4 + tr[4]) * 16;
      int sel = -1, n1 = 0;
#pragma unroll
      for (int j = 0; j < 16; ++j) { if (pt[j]) { if (n1 == lane) sel = j; ++n1; } }
      if (sel < 0) {
        int n0 = 0, want = lane - n1;
#pragma unroll
        for (int j = 0; j < 16; ++j) if (!pt[j]) { if (n0 == want) { sel = j; break; } ++n0; }
      }
      int cy = sel >> 2, cx = sel & 3;
      int x  = cx + tr[1] - 2;
      int y  = cy + tr[2];
      int ny = y + tr[3];
      bool mask = (y >= 0) && (ny >= 0);
      bool xok  = (x >= 0) && (x < 10);
      bool v1 = mask && xok && (y < 21);
      bool v2 = mask && xok && (ny < 21);
      pcs[2 * lane + 0]       = v1 ? y  : -100;
      pcs[2 * lane + 1]       = x + 1;
      pcs[2 * (lane + 4)]     = v2 ? ny : -100;
      pcs[2 * (lane + 4) + 1] = x + 1;
    }
    __builtin_amdgcn_wave_barrier();

    float* ob = out_board + (size_t)(bb + wv) * 792;
    for (int v = lane; v < 198; v += 64) {
      int j0 = v * 4;
      int ch = j0 / 264, rem = j0 - ch * 264;
      int r = rem / 12, c = rem - r * 12;
      float val[4];
      if (ch == 0) {
#pragma unroll
        for (int d = 0; d < 4; ++d) {
          int cd = c + d;
          val[d] = (r == 21 || cd == 0 || cd == 11) ? 1.f
                 : W[(r + 2) * RS + cd + 4];
        }
      } else {
#pragma unroll
        for (int d = 0; d < 4; ++d) {
          int cd = c + d;
          val[d] = (r == 21 || cd == 0 || cd == 11) ? 1.f : 0.f;
        }
#pragma unroll
        for (int e = 0; e < 4; ++e) {
          int pr = pcs[2 * ((ch - 1) * 4 + e)];
          int pc = pcs[2 * ((ch - 1) * 4 + e) + 1];
          if (pr == r && (unsigned)(pc - c) < 4u) val[pc - c] = 1.f;
        }
      }
      *(float4*)(ob + j0) = float4{val[0], val[1], val[2], val[3]};
    }
  }
  __syncthreads();

  // ------- Phase B: fused conv1+relu+pool1; wave = sample, lane = position <60 -------
  if (lane < 60) {
    int p = lane;
    int r = p / 6, c = p - r * 6;
    const float* Wq  = &scr[wv * SS2];
    const int*   pcs = (const int*)&scr[wv * SS2 + PCSOFF];
    f32x2 acc2[2][2][3];                      // [i][j][o2]; pairs over o
#pragma unroll
    for (int i = 0; i < 2; ++i)
#pragma unroll
      for (int j = 0; j < 2; ++j) {
        int pcell = (2 * r + i) * 12 + (2 * c + j);
#pragma unroll
        for (int o2 = 0; o2 < 3; ++o2) {
          f32x2 cb2 = *(const f32x2*)&cbL[pcell * 6 + 2 * o2];
          acc2[i][j][o2] = f32x2{b1[2 * o2] + cb2.x, b1[2 * o2 + 1] + cb2.y};
        }
      }

    // dense ch0 rolling-row (300 pk-FMA); weight pairs via GLOBAL uniform -> SGPR-64
    {
      const float* base = Wq + (2 * r) * RS + (2 * c + 2);
#pragma unroll
      for (int u = 0; u < 6; ++u) {
        float2 a0 = *(const float2*)(base + u * RS);
        float2 a1 = *(const float2*)(base + u * RS + 2);
        float2 a2 = *(const float2*)(base + u * RS + 4);
        float rv[6] = {a0.x, a0.y, a1.x, a1.y, a2.x, a2.y};
#pragma unroll
        for (int i = 0; i < 2; ++i) {
          if (u - i < 0 || u - i > 4) continue;   // folds at compile time
          const int ky = u - i;
#pragma unroll
          for (int j = 0; j < 2; ++j)
#pragma unroll
            for (int kx = 0; kx < 5; ++kx) {
              float xv = rv[j + kx];
              int tap = ky * 5 + kx;
#pragma unroll
              for (int o2 = 0; o2 < 3; ++o2)
                acc2[i][j][o2] += w1p2[tap * 3 + o2] * xv;   // v_pk_fma_f32
            }
        }
      }
    }

    // sparse piece taps (divergent -> w1L, scalar adds into pair halves)
#pragma unroll
    for (int e = 0; e < 8; ++e) {
      int pr = pcs[2 * e];
      if (pr < 0) continue;
      int pc = pcs[2 * e + 1];
      int chm = e >> 2;
      int dyb = pr + 2 - 2 * r;
      int dxb = pc + 2 - 2 * c;
      if (dyb < 0 || dyb > 5 || dxb < 0 || dxb > 5) continue;
#pragma unroll
      for (int i = 0; i < 2; ++i) {
        int dy = dyb - i;
        if ((unsigned)dy >= 5u) continue;
#pragma unroll
        for (int j = 0; j < 2; ++j) {
          int dx = dxb - j;
          if ((unsigned)dx >= 5u) continue;
#pragma unroll
          for (int o = 0; o < 6; ++o)
            acc2[i][j][o >> 1][o & 1] += w1L[(o * 2 + chm) * 25 + dy * 5 + dx];
        }
      }
    }

    float* P1q = &scr[wv * SS2 + P1OFF];
#pragma unroll
    for (int o = 0; o < 6; ++o) {
      float v = fmaxf(acc2[0][0][o >> 1][o & 1], 0.f) + fmaxf(acc2[0][1][o >> 1][o & 1], 0.f)
              + fmaxf(acc2[1][0][o >> 1][o & 1], 0.f) + fmaxf(acc2[1][1][o >> 1][o & 1], 0.f);
      P1q[o * 61 + p] = 0.25f * v;
    }
  }
  __syncthreads();

  // ------- conv2+relu: wave wvu -> oc [4wvu,4wvu+4), pairs over oc; all samples -------
  const int wvu = __builtin_amdgcn_readfirstlane(wv);

  if (lane < 48) {
    int q = lane / 12, p = lane - q * 12;
    int r = p >> 1, c = p & 1;
    const float* P1q = &scr[q * SS2 + P1OFF];
    f32x2 a2[2];                               // oc pairs {4wvu,+1},{+2,+3}
    a2[0] = f32x2{b2w[4 * wvu], b2w[4 * wvu + 1]};
    a2[1] = f32x2{b2w[4 * wvu + 2], b2w[4 * wvu + 3]};
    for (int ic = 0; ic < 6; ++ic)
#pragma unroll
      for (int kr = 0; kr < 5; ++kr) {
        float xv[5];
#pragma unroll
        for (int kc = 0; kc < 5; ++kc)
          xv[kc] = P1q[ic * 61 + (r + kr) * 6 + c + kc];
#pragma unroll
        for (int kc = 0; kc < 5; ++kc) {
          int tap = (ic * 5 + kr) * 5 + kc;
          a2[0] += w2p2[tap * 8 + 2 * wvu] * xv[kc];       // v_pk_fma_f32
          a2[1] += w2p2[tap * 8 + 2 * wvu + 1] * xv[kc];
        }
      }
    float* C2q = &scr[q * SS2];
#pragma unroll
    for (int oo = 0; oo < 4; ++oo)
      C2q[(4 * wvu + oo) * 12 + p] = fmaxf(a2[oo >> 1][oo & 1], 0.f);
  }
  __syncthreads();

  // ---------------- per-wave tail: wave q owns sample q ----------------
  {
    const int q = wvu;
    float* S = &scr[q * SS2];

    if (lane < 48) {
      int o = lane / 3, pr = lane - o * 3;
      float v = 0.25f * (S[o * 12 + 4 * pr] + S[o * 12 + 4 * pr + 1]
                       + S[o * 12 + 4 * pr + 2] + S[o * 12 + 4 * pr + 3]);
      S[192 + lane] = v;
    }
    __builtin_amdgcn_wave_barrier();

    // conv3+relu: lane = out channel; K pairs (both operands per-lane 64-bit)
    {
      int o = lane;
      const f32x2* w3r = (const f32x2*)(w3 + o * 48);
      f32x2 accp = f32x2{b3[o], 0.f};
#pragma unroll
      for (int k2 = 0; k2 < 24; ++k2)
        accp += *(const f32x2*)(S + 192 + 2 * k2) * w3r[k2];
      S[240 + o] = fmaxf(accp.x + accp.y, 0.f);
    }
    __builtin_amdgcn_wave_barrier();

    // fc1+relu: j=lane&31, k-half split + pk + shfl combine
    {
      int j = lane & 31, h = lane >> 5;
      const f32x2* wr = (const f32x2*)(wf1 + j * 64 + 32 * h);
      f32x2 accp = f32x2{0.f, 0.f};
#pragma unroll
      for (int k2 = 0; k2 < 16; ++k2)
        accp += *(const f32x2*)(S + 240 + 32 * h + 2 * k2) * wr[k2];
      float part = accp.x + accp.y;
      part += __shfl_xor(part, 32, 64);
      if (h == 0) {
        float acc = fmaxf(bf1[j] + part, 0.f);
        S[304 + j] = acc;
        out[(size_t)(bb + q) * 96 + 64 + j] = acc;
      }
    }
    __builtin_amdgcn_wave_barrier();

    // lanes 0..31: v = ipw[64:96] @ b2 + ipb ; lanes 32..63: xf (independent)
    {
      int j = lane & 31;
      if (lane < 32) {
        const f32x2* wr = (const f32x2*)(ipw + (64 + j) * 32);
        f32x2 accp = f32x2{ipb[64 + j], 0.f};
#pragma unroll
        for (int k2 = 0; k2 < 16; ++k2)
          accp += *(const f32x2*)(S + 304 + 2 * k2) * wr[k2];
        S[336 + j] = accp.x + accp.y;
      } else {
        const int* tr = t + (size_t)(bb + q) * 232;
        const f32x2* wr = (const f32x2*)(fcw + j * 8);
        f32x2 accp = f32x2{fcb[j], 0.f};
#pragma unroll
        for (int k2 = 0; k2 < 4; ++k2) {
          f32x2 tv = f32x2{(float)tr[2 * k2], (float)tr[2 * k2 + 1]};
          accp += tv * wr[k2];
        }
        out[(size_t)(bb + q) * 96 + j] = fmaxf(accp.x + accp.y, 0.f);
      }
    }
    __builtin_amdgcn_wave_barrier();

    // a_mean = opw @ v + opb
    if (lane < 32) {
      int j = lane;
      const f32x2* wr = (const f32x2*)(opw + j * 32);
      f32x2 accp = f32x2{opb[j], 0.f};
#pragma unroll
      for (int k2 = 0; k2 < 16; ++k2)
        accp += *(const f32x2*)(S + 336 + 2 * k2) * wr[k2];
      out[(size_t)(bb + q) * 96 + 32 + j] = accp.x + accp.y;
    }
  }
}

extern "C" void kernel_launch(void* const* d_in, const int* in_sizes, int n_in,
                              void* d_out, int out_size, void* d_ws, size_t ws_size,
                              hipStream_t stream) {
  const int*   t   = (const int*)d_in[0];
  const int*   pt  = (const int*)d_in[1];
  const float* w1  = (const float*)d_in[2];
  const float* b1  = (const float*)d_in[3];
  const float* w2  = (const float*)d_in[4];
  const float* b2w = (const float*)d_in[5];
  const float* w3  = (const float*)d_in[6];
  const float* b3  = (const float*)d_in[7];
  const float* wf1 = (const float*)d_in[8];
  const float* bf1 = (const float*)d_in[9];
  const float* fcw = (const float*)d_in[10];
  const float* fcb = (const float*)d_in[11];
  // d_in[12] = emb : dead (softmax over singleton axis == 1)
  const float* ipw = (const float*)d_in[13];
  const float* ipb = (const float*)d_in[14];
  const float* opw = (const float*)d_in[15];
  const float* opb = (const float*)d_in[16];

  float* out       = (float*)d_out;
  float* out_board = out + (size_t)BATCH * 96;
  float* ws        = (float*)d_ws;     // 4134 floats

  hipLaunchKernelGGL(precomp_kernel, dim3(17), dim3(256), 0, stream, w1, w2, ws);
  hipLaunchKernelGGL(board_model_kernel, dim3(NBLK), dim3(256), 0, stream,
                     t, pt, w1, b1, b2w, w3, b3, wf1, bf1, fcw, fcb,
                     ipw, ipb, opw, opb, ws, out, out_board);
}